// Round 10
// baseline (164.538 us; speedup 1.0000x reference)
//
#include <hip/hip_runtime.h>
#include <hip/hip_bf16.h>

typedef __bf16 bf16;
typedef __attribute__((ext_vector_type(8))) __bf16 bf16x8;
typedef __attribute__((ext_vector_type(2))) __bf16 bf16x2;
typedef __attribute__((ext_vector_type(4))) float f32x4;
typedef __attribute__((ext_vector_type(4))) unsigned int uint4v;

#define C_NODES 63
#define F_DIM   250
#define NEG_SLOPE 0.2f

// LDS: A-fragments of X only (swzA), 32 KiB. H, scores, alpha all stay in
// registers (shuffle-redistributed). ONE barrier total.
#define LDS_BYTES 32768

// A-frag swizzle: bank-uniform staging writes, bijective reads.
__device__ __forceinline__ int swzA(int a) {
    return a ^ ((((a >> 8) & 3) ^ ((a >> 10) & 3)) << 4) ^ (((a >> 12) & 1) << 6);
}

// Pack W (250x250 f32) into bf16 MFMA-B fragment order, padded to 256x256.
// Columns 250/251 hold ws = W@att_src and wd = W@att_dst, so GEMM1 emits the
// per-node scores a_s, a_d directly. Rows k>=250 are zero (kills A-garbage).
extern "C" __global__ __launch_bounds__(256)
void gat_prep(const float* __restrict__ W, const float* __restrict__ att_src,
              const float* __restrict__ att_dst, bf16* __restrict__ Wp) {
    int i = blockIdx.x * 256 + threadIdx.x;   // 0..65535
    int tile = i >> 9;
    int ln   = (i >> 3) & 63;
    int j    = i & 7;
    int kt = tile >> 4, nt = tile & 15;
    int k = kt * 32 + (ln >> 4) * 8 + j;
    int n = nt * 16 + (ln & 15);
    float v = 0.f;
    if (k < F_DIM) {
        if (n < F_DIM) {
            v = W[k * F_DIM + n];
        } else if (n == F_DIM || n == F_DIM + 1) {
            const float* att = (n == F_DIM) ? att_src : att_dst;
            float s = 0.f;
            for (int o = 0; o < F_DIM; ++o) s = fmaf(W[k * F_DIM + o], att[o], s);
            v = s;
        }
    }
    Wp[i] = (bf16)v;
}

// 512 threads = 8 waves; wave w owns output cols [w*32, w*32+32).
// Every wave ALSO computes B-tile 15 (cols 240-255: includes score cols
// 250/251) so scores are wave-local -> zero cross-wave traffic after staging.
extern "C" __global__ __launch_bounds__(512, 4)
void gat_main(const float* __restrict__ x, const bf16* __restrict__ Wp,
              const float* __restrict__ bias, float* __restrict__ out)
{
    __shared__ __align__(16) unsigned char smem[LDS_BYTES];
    const int tid  = threadIdx.x;
    const int lane = tid & 63;
    const int w    = tid >> 6;        // wave id 0..7
    const int b    = blockIdx.x;
    const int fl   = lane & 15;
    const int fh   = lane >> 4;

    const bf16x8* wpv = (const bf16x8*)Wp;

    // NaN-guard: zero the only A-frag slots the scatter never writes.
    if (tid < 64) {
        // c in 250..255 tail: tile (mt,7), dl=48+(r&15), bytes 4..15
        int base = swzA((((tid >> 4) * 8 + 7) << 10) + (48 + (tid & 15)) * 16);
        *(unsigned int*)(smem + base + 4) = 0u;
        *(unsigned long long*)(smem + base + 8) = 0ull;
    } else if (tid < 96) {
        // row r=63: tile (3,kt), dl=((g&3)<<4)|15, full 16 B
        int idx = tid - 64;
        int base = swzA(((24 + (idx >> 2)) << 10) + ((((idx & 3) << 4) | 15) * 16));
        *(f32x4*)(smem + base) = (f32x4){0.f, 0.f, 0.f, 0.f};
    }

    // stage X_b -> bf16 A-fragments (swzA): 63 rows x 32 col-groups.
    {
        const float* xb = x + (size_t)b * (C_NODES * F_DIM);
#pragma unroll
        for (int it = 0; it < 4; ++it) {
            int idx = tid + it * 512;
            if (idx < 2016) {
                int r = idx >> 5, g = idx & 31;
                const float* src = xb + r * F_DIM + g * 8;
                int dl = (r & 15) | ((g & 3) << 4);
                int base = swzA((((r >> 4) * 8 + (g >> 2)) << 10) + dl * 16);
                if (g < 31) {
                    float2 v0 = *(const float2*)(src);
                    float2 v1 = *(const float2*)(src + 2);
                    float2 v2 = *(const float2*)(src + 4);
                    float2 v3 = *(const float2*)(src + 6);
                    bf16x8 pk8 = { (bf16)v0.x, (bf16)v0.y, (bf16)v1.x, (bf16)v1.y,
                                   (bf16)v2.x, (bf16)v2.y, (bf16)v3.x, (bf16)v3.y };
                    *(bf16x8*)(smem + base) = pk8;
                } else {
                    // tail: only c=248,249 valid; j>=2 zeroed by guard
                    float2 v0 = *(const float2*)(src);
                    bf16x2 pk2 = { (bf16)v0.x, (bf16)v0.y };
                    *(bf16x2*)(smem + base) = pk2;
                }
            }
        }
    }
    __syncthreads();   // THE barrier: A-frags ready; waves autonomous after.

    // ---- GEMM1: wave's 2 own B-tiles + score tile 15 ----
    f32x4 acc[4][2];
    f32x4 acc15[4];
#pragma unroll
    for (int mt = 0; mt < 4; ++mt) {
        acc[mt][0] = (f32x4){0.f, 0.f, 0.f, 0.f};
        acc[mt][1] = (f32x4){0.f, 0.f, 0.f, 0.f};
        acc15[mt]  = (f32x4){0.f, 0.f, 0.f, 0.f};
    }
#pragma unroll 1
    for (int kt = 0; kt < 8; ++kt) {
        bf16x8 bw0 = wpv[(kt * 16 + w * 2)     * 64 + lane];
        bf16x8 bw1 = wpv[(kt * 16 + w * 2 + 1) * 64 + lane];
        bf16x8 bwS = wpv[(kt * 16 + 15)        * 64 + lane];
#pragma unroll
        for (int mt = 0; mt < 4; ++mt) {
            bf16x8 af = *(const bf16x8*)(smem + swzA(((mt * 8 + kt) << 10) + lane * 16));
            acc[mt][0] = __builtin_amdgcn_mfma_f32_16x16x32_bf16(af, bw0, acc[mt][0], 0, 0, 0);
            acc[mt][1] = __builtin_amdgcn_mfma_f32_16x16x32_bf16(af, bw1, acc[mt][1], 0, 0, 0);
            acc15[mt]  = __builtin_amdgcn_mfma_f32_16x16x32_bf16(af, bwS, acc15[mt], 0, 0, 0);
        }
    }

    // ---- pack H (C-frag) to bf16 pairs: pk[mt][nti][h] = {i=2h, i=2h+1} ----
    unsigned int pk[4][2][2];
#pragma unroll
    for (int mt = 0; mt < 4; ++mt)
#pragma unroll
        for (int nti = 0; nti < 2; ++nti) {
            f32x4 v = acc[mt][nti];
            bf16x2 p0 = { (bf16)v.x, (bf16)v.y };
            bf16x2 p1 = { (bf16)v.z, (bf16)v.w };
            pk[mt][nti][0] = __builtin_bit_cast(unsigned int, p0);
            pk[mt][nti][1] = __builtin_bit_cast(unsigned int, p1);
        }

    // ---- in-register transpose: build GEMM2 B-frags hb[nti][kt2] ----
    // dest (fh,fl) j: row kt2*32+fh*8+j, col w*32+nti*16+fl
    //   <- src lane ((fh&1)*2+(j>>2))*16+fl, tile mt=kt2*2+(fh>>1), reg i=j&3
    const int LA = ((fh & 1) << 5) + fl;
    const int LB = LA + 16;
    const bool fhHi = (fh & 2) != 0;
    uint4v hb[2][2];
#pragma unroll
    for (int nti = 0; nti < 2; ++nti)
#pragma unroll
        for (int kt2 = 0; kt2 < 2; ++kt2) {
            unsigned int u[4];
#pragma unroll
            for (int h = 0; h < 2; ++h) {
                unsigned int a0 = __shfl(pk[kt2 * 2][nti][h],     LA);
                unsigned int a1 = __shfl(pk[kt2 * 2 + 1][nti][h], LA);
                u[h] = fhHi ? a1 : a0;
                unsigned int b0 = __shfl(pk[kt2 * 2][nti][h],     LB);
                unsigned int b1 = __shfl(pk[kt2 * 2 + 1][nti][h], LB);
                u[2 + h] = fhHi ? b1 : b0;
            }
            hb[nti][kt2] = (uint4v){u[0], u[1], u[2], u[3]};
        }

    // ---- gather a_s (cols this lane needs: s = kt2*32+fh*8+j) ----
    // a_s[s] lives in acc15[s>>4][s&3] at lane ((s>>2)&3)*16 + 10
    float asv[16];
#pragma unroll
    for (int kt2 = 0; kt2 < 2; ++kt2)
#pragma unroll
        for (int j = 0; j < 8; ++j) {
            int Ls = (((fh & 1) * 2 + (j >> 2)) << 4) + 10;
            float c0 = __shfl(acc15[kt2 * 2][j & 3],     Ls);
            float c1 = __shfl(acc15[kt2 * 2 + 1][j & 3], Ls);
            asv[kt2 * 8 + j] = fhHi ? c1 : c0;
        }
    // ---- gather a_d for rows d = mt*16+fl (lane ((fl>>2)*16+11), i=fl&3) ----
    float adv[4];
    {
        int Ld = ((fl >> 2) << 4) + 11;
#pragma unroll
        for (int mt = 0; mt < 4; ++mt) {
            float t0 = __shfl(acc15[mt][0], Ld);
            float t1 = __shfl(acc15[mt][1], Ld);
            float t2 = __shfl(acc15[mt][2], Ld);
            float t3 = __shfl(acc15[mt][3], Ld);
            float s01 = (fl & 1) ? t1 : t0;
            float s23 = (fl & 1) ? t3 : t2;
            adv[mt] = (fl & 2) ? s23 : s01;
        }
    }

    // ---- per-wave softmax (rows d=mt*16+fl; reduce across fh via xor16/32)
    //      directly into A-frags, then GEMM2 ----
    f32x4 acc2[4][2];
#pragma unroll
    for (int mt = 0; mt < 4; ++mt) {
        float p[16];
#pragma unroll
        for (int k = 0; k < 16; ++k) {
            float e = asv[k] + adv[mt];
            p[k] = (e > 0.f) ? e : NEG_SLOPE * e;
        }
        if (fh == 3) p[15] = -3.0e38f;   // s=63 excluded (63 sources)
        float md = p[0];
#pragma unroll
        for (int k = 1; k < 16; ++k) md = fmaxf(md, p[k]);
        md = fmaxf(md, __shfl_xor(md, 16));
        md = fmaxf(md, __shfl_xor(md, 32));
        float sum = 0.f;
#pragma unroll
        for (int k = 0; k < 16; ++k) { p[k] = __expf(p[k] - md); sum += p[k]; }
        sum += __shfl_xor(sum, 16);
        sum += __shfl_xor(sum, 32);
        float rz = 1.f / sum;
        bf16x8 aal0, aal1;
#pragma unroll
        for (int k = 0; k < 8; ++k) {
            aal0[k] = (bf16)(p[k] * rz);
            aal1[k] = (bf16)(p[8 + k] * rz);
        }
        acc2[mt][0] = (f32x4){0.f, 0.f, 0.f, 0.f};
        acc2[mt][1] = (f32x4){0.f, 0.f, 0.f, 0.f};
#pragma unroll
        for (int nti = 0; nti < 2; ++nti) {
            bf16x8 h0 = __builtin_bit_cast(bf16x8, hb[nti][0]);
            bf16x8 h1 = __builtin_bit_cast(bf16x8, hb[nti][1]);
            acc2[mt][nti] = __builtin_amdgcn_mfma_f32_16x16x32_bf16(aal0, h0, acc2[mt][nti], 0, 0, 0);
            acc2[mt][nti] = __builtin_amdgcn_mfma_f32_16x16x32_bf16(aal1, h1, acc2[mt][nti], 0, 0, 0);
        }
    }

    // epilogue: + bias (L2-hot), store fp32, mask r<63 / f<250
    float bv[2];
#pragma unroll
    for (int nti = 0; nti < 2; ++nti) {
        int f = w * 32 + nti * 16 + fl;
        bv[nti] = (f < F_DIM) ? bias[f] : 0.f;
    }
    float* ob = out + (size_t)b * (C_NODES * F_DIM);
#pragma unroll
    for (int mt = 0; mt < 4; ++mt) {
#pragma unroll
        for (int i = 0; i < 4; ++i) {
            int r = mt * 16 + fh * 4 + i;
            if (r < C_NODES) {
#pragma unroll
                for (int nti = 0; nti < 2; ++nti) {
                    int f = w * 32 + nti * 16 + fl;
                    if (f < F_DIM) ob[r * F_DIM + f] = acc2[mt][nti][i] + bv[nti];
                }
            }
        }
    }
}

extern "C" void kernel_launch(void* const* d_in, const int* in_sizes, int n_in,
                              void* d_out, int out_size, void* d_ws, size_t ws_size,
                              hipStream_t stream) {
    const float* x       = (const float*)d_in[0];
    const float* W       = (const float*)d_in[1];
    const float* att_src = (const float*)d_in[2];
    const float* att_dst = (const float*)d_in[3];
    const float* bias    = (const float*)d_in[4];
    float* out = (float*)d_out;
    bf16* Wp = (bf16*)d_ws;   // 65536 bf16 = 128 KB packed W (+score cols)

    gat_prep<<<256, 256, 0, stream>>>(W, att_src, att_dst, Wp);
    gat_main<<<4096, 512, 0, stream>>>(x, Wp, bias, out);
}